// Round 1
// 80.231 us; speedup vs baseline: 1.0147x; 1.0147x over previous
//
#include <hip/hip_runtime.h>
#include <math.h>

#define HH 512
#define WW 512
#define NA 180
#define ND 729
#define NB 2

// ws layout (float units):
//   [1024, 1024+360)   interleaved {cos,sin} per angle
//   [2048, 2048+360)   row edge f[0]   (batch-major: blk = b*NA + a)
//   [2432, 2432+360)   row edge f[728]
//   [4096, ...)        filtered sinograms
#define WS_CS 1024
#define WS_E0 2048
#define WS_E7 2432
#define WS_FILT 4096

// Ram-Lak spatial kernel (closed form, validated R2-R7):
//   g[d] = (0.125 + min(d,729-d)/1458)/729 — piecewise LINEAR in d, so the
// 729-tap circular convolution is O(1) per output via prefix moments
//   P[k] = sum_{j<k} x[j],  Q[k] = sum_{j<k} j*x[j]  (double precision):
//   filtered[n] = c0*X + c1*(A(n)+B(n)), c0 = 0.125/729, c1 = 1/(1458*729)
//   A(n) = sum_{d=1..364} d*x[(n-d)%729], B(n) = sum_{d=1..364} d*x[(n+d)%729]
// NO fence / atomic / last-block-done: R5+R7 showed __threadfence() in every
// block costs ~40us; separate nodes are ~8-10us. One block per row; block 360
// writes the angle tables.
// R8: LDS Hillis-Steele (16 barriers) -> wave shfl_up Kogge-Stone + 4-wide
// cross-wave combine (2 barriers); xs[] LDS staging dropped (registers);
// row edges f[0]/f[728] stashed compactly for k_bp.
__global__ __launch_bounds__(256, 1) void k_filter(const float* __restrict__ sino,
                                                   float* __restrict__ ws) {
    int blk = blockIdx.x;
    int tid = threadIdx.x;
    if (blk == 360) {   // angle tables
        for (int t = tid; t < NA; t += 256) {
            double ang = M_PI * (double)t / (double)(NA - 1);
            ws[WS_CS + 2 * t] = (float)cos(ang);
            ws[WS_CS + 2 * t + 1] = (float)sin(ang);
        }
        return;
    }
    __shared__ double Pd[730], Qd[730];
    __shared__ double wsx[4], wsq[4];
    const float* x = sino + blk * ND;
    int lane = tid & 63;
    int w = tid >> 6;
    int j0 = 3 * tid;
    double v0 = 0.0, v1 = 0.0, v2 = 0.0;
    double lx = 0.0, lq = 0.0;
    if (tid < 243) {
        v0 = (double)x[j0];
        v1 = (double)x[j0 + 1];
        v2 = (double)x[j0 + 2];
        lx = v0 + v1 + v2;
        lq = (double)j0 * v0 + (double)(j0 + 1) * v1 + (double)(j0 + 2) * v2;
    }
    // wave-level inclusive Kogge-Stone scan (no barriers)
    double ix = lx, iq = lq;
    #pragma unroll
    for (int off = 1; off < 64; off <<= 1) {
        double tx = __shfl_up(ix, off);
        double tq = __shfl_up(iq, off);
        if (lane >= off) { ix += tx; iq += tq; }
    }
    if (lane == 63) { wsx[w] = ix; wsq[w] = iq; }
    __syncthreads();
    double w0 = wsx[0], w1 = wsx[1], w2 = wsx[2], w3 = wsx[3];
    double q0 = wsq[0], q1 = wsq[1], q2 = wsq[2], q3 = wsq[3];
    double bx = 0.0, bq = 0.0;
    if (w > 0) { bx += w0; bq += q0; }
    if (w > 1) { bx += w1; bq += q1; }
    if (w > 2) { bx += w2; bq += q2; }
    ix += bx;                    // inclusive over 256 threads
    iq += bq;
    const double X = w0 + w1 + w2 + w3;
    const double M = q0 + q1 + q2 + q3;
    if (tid < 243) {             // exclusive P[0..728], Q[0..728]
        double bp_ = ix - lx;    // exclusive = inclusive - local (double: ~1e-16 rel)
        double bq_ = iq - lq;
        Pd[j0] = bp_;     Qd[j0] = bq_;
        bp_ += v0;        bq_ += (double)j0 * v0;
        Pd[j0 + 1] = bp_; Qd[j0 + 1] = bq_;
        bp_ += v1;        bq_ += (double)(j0 + 1) * v1;
        Pd[j0 + 2] = bp_; Qd[j0 + 2] = bq_;
    }
    if (tid == 0) { Pd[ND] = X; Qd[ND] = M; }
    __syncthreads();
    const double c0 = 0.125 / 729.0;
    const double c1 = 1.0 / (1458.0 * 729.0);
    float* f = ws + WS_FILT + blk * ND;
    for (int n = tid; n < ND; n += 256) {
        double dn = (double)n;
        double A, Bv;
        if (n >= 364) A = dn * (Pd[n] - Pd[n - 364]) - (Qd[n] - Qd[n - 364]);
        else          A = dn * Pd[n] - Qd[n]
                        + (dn + 729.0) * (X - Pd[n + 365]) - (M - Qd[n + 365]);
        if (n <= 364) Bv = (Qd[n + 365] - Qd[n + 1]) - dn * (Pd[n + 365] - Pd[n + 1]);
        else          Bv = (M - Qd[n + 1]) - dn * (X - Pd[n + 1])
                         + Qd[n - 364] + (729.0 - dn) * Pd[n - 364];
        float fv = (float)(c0 * X + c1 * (A + Bv));
        f[n] = fv;
        if (n == 0)           ws[WS_E0 + blk] = fv;   // compact edges for k_bp
        else if (n == ND - 1) ws[WS_E7 + blk] = fv;
    }
}

// Backprojection. idx(a) = clip(trunc((rot*c1)*729), 0, 728), rot = xc*cos+yc*sin.
// For r>=16 the angle axis splits into [low | band | high | band | low]:
//   high (idx=728): rot >= 6.27457  <=>  |a-phi| <= theta, theta = acos(6.27457/r)
//   low  (idx=0):   rot <  0.008619 <=>  |a-phi| >  ~pi/2
// Edges via atan2f/acosf (+-1 index guard, ~250x margin); guarded band uses
// exact original arithmetic; clamped cores use P0/P728 prefix sums computed
// IN-BLOCK: R8 version loads the compact edge arrays (contiguous, not the old
// 360 stride-2916B gathers) and scans via shfl_up (2 barriers, was 16).
__global__ __launch_bounds__(256) void k_bp(const float* __restrict__ ws,
                                            float* __restrict__ out) {
    const float* __restrict__ tab = ws + WS_CS;
    __shared__ float wm0[4], wm1[4];
    __shared__ float P0s[NA + 1], P7s[NA + 1];
    int tid = threadIdx.x;
    int p = blockIdx.x * 256 + tid;
    int b = p / (HH * WW);
    const float* f = ws + WS_FILT + b * (NA * ND);
    int lane = tid & 63;
    int w = tid >> 6;
    float v0 = 0.f, v1 = 0.f;
    if (tid < NA) {
        v0 = ws[WS_E0 + b * NA + tid];
        v1 = ws[WS_E7 + b * NA + tid];
    }
    float i0 = v0, i1 = v1;
    #pragma unroll
    for (int off = 1; off < 64; off <<= 1) {
        float t0 = __shfl_up(i0, off);
        float t1 = __shfl_up(i1, off);
        if (lane >= off) { i0 += t0; i1 += t1; }
    }
    if (lane == 63) { wm0[w] = i0; wm1[w] = i1; }
    __syncthreads();
    float b0 = 0.f, b1 = 0.f;
    if (w > 0) { b0 += wm0[0]; b1 += wm1[0]; }
    if (w > 1) { b0 += wm0[1]; b1 += wm1[1]; }
    if (w > 2) { b0 += wm0[2]; b1 += wm1[2]; }
    if (tid == 0) { P0s[0] = 0.f; P7s[0] = 0.f; }
    if (tid < NA) { P0s[tid + 1] = i0 + b0; P7s[tid + 1] = i1 + b1; }
    __syncthreads();
    int rem = p - b * (HH * WW);
    int y = rem / WW;
    int x = rem - y * WW;
    float xc = (float)x - (WW * 0.5f);
    float yc = (float)y - (HH * 0.5f);
    float acc = 0.f;
    float r2 = xc * xc + yc * yc;
    if (r2 < 256.0f) {
        for (int a = 0; a < NA; ++a) {
            float c = tab[2 * a], s = tab[2 * a + 1];
            float rot = xc * c + yc * s;
            float t = (rot * 0.15915494309189535f) * 729.0f;
            int i = (int)t;
            i = i < 0 ? 0 : (i > (ND - 1) ? (ND - 1) : i);
            acc += f[a * ND + i];
        }
    } else {
        float r = sqrtf(r2);
        float phi = atan2f(yc, xc);
        float cen = (phi < -1.5707964f) ? phi + 6.2831855f : phi;
        float theta = acosf(6.27457f / r);
        float tc = cen * 56.971835f;                 // *(179/pi)
        float w_ = theta * 56.971835f;
        int hs = (int)ceilf(tc - w_) + 1;
        int he = (int)floorf(tc + w_) - 1;
        int le = (int)floorf(tc - 89.5f) - 1;
        int rs = (int)ceilf(tc + 89.5f) + 1;
        hs = hs < 0 ? 0 : hs;
        he = he > (NA - 1) ? (NA - 1) : he;
        if (le >= 0) acc += P0s[le + 1];
        if (rs <= NA - 1) acc += P0s[NA] - P0s[rs];
        if (he >= hs) acc += P7s[he + 1] - P7s[hs];
        int b1s = le + 1 < 0 ? 0 : le + 1;
        int b1e = hs - 1 > (NA - 1) ? (NA - 1) : hs - 1;
        int b2s = he + 1 < 0 ? 0 : he + 1;
        int b2e = rs - 1 > (NA - 1) ? (NA - 1) : rs - 1;
        for (int a = b1s; a <= b1e; ++a) {
            float c = tab[2 * a], s = tab[2 * a + 1];
            float rot = xc * c + yc * s;
            float t = (rot * 0.15915494309189535f) * 729.0f;
            int i = (int)t;
            i = i < 0 ? 0 : (i > (ND - 1) ? (ND - 1) : i);
            acc += f[a * ND + i];
        }
        for (int a = b2s; a <= b2e; ++a) {
            float c = tab[2 * a], s = tab[2 * a + 1];
            float rot = xc * c + yc * s;
            float t = (rot * 0.15915494309189535f) * 729.0f;
            int i = (int)t;
            i = i < 0 ? 0 : (i > (ND - 1) ? (ND - 1) : i);
            acc += f[a * ND + i];
        }
    }
    out[p] = fmaxf(acc * (float)(M_PI / NA), 0.0f);  // clip(.,0,max) == relu
}

extern "C" void kernel_launch(void* const* d_in, const int* in_sizes, int n_in,
                              void* d_out, int out_size, void* d_ws, size_t ws_size,
                              hipStream_t stream) {
    const float* sino = (const float*)d_in[0];
    float* out = (float*)d_out;
    float* ws = (float*)d_ws;

    hipLaunchKernelGGL(k_filter, dim3(361), dim3(256), 0, stream, sino, ws);
    hipLaunchKernelGGL(k_bp, dim3((NB * HH * WW) / 256), dim3(256), 0, stream, ws, out);
}